// Round 6
// baseline (365.302 us; speedup 1.0000x reference)
//
#include <hip/hip_runtime.h>
#include <hip/hip_bf16.h>
#include <math.h>

#define NB 8192
#define G 4                 // batch rows per block (amortizes W streaming + uv compute)
#define NBLK (NB / G)
#define NNODES 32
#define TT 3
#define DIM 128
#define HID 128
#define HSTR 132            // padded LDS row stride (floats), rows stay 16B-aligned

__global__ __launch_bounds__(256) void gat_main(
    const float* __restrict__ hg,     // (B,32,128) fp32
    const int* __restrict__ maskg,    // (3,B,32) 4-byte bool words (verified round 5)
    const float* __restrict__ Wg,     // (3,128,128) fp32
    const float* __restrict__ ag,     // (3,256,1) fp32
    float* __restrict__ outg)         // (B,128) fp32  <-- the round-5 fix
{
    __shared__ float hL[NNODES * HSTR];   // current row's h[b]
    __shared__ float uvL[12 * HSTR];      // 12 projected vectors (computed in-block)
    __shared__ float aL[TT * 2 * HID];    // staged a (768 floats)
    __shared__ float sTop[9];             // [i*3+j]
    __shared__ float sNb[TT * NNODES];
    __shared__ float vv[TT * NNODES];     // per-node combine weights
    __shared__ float gAll[G * TT * DIM];  // weighted features, all G rows
    __shared__ float pL[8 * G * DIM];     // epilogue partials

    const int tid = threadIdx.x;
    const int b0 = blockIdx.x * G;

    // ---- stage a ----
    for (int i = tid; i < TT * 2 * HID; i += 256) aL[i] = ag[i];
    __syncthreads();

    // ---- compute uv in-block: uv[e][d], e<9: u[i=e/3][j=e%3] = W[i]^T-row-d . a_top[j];
    //      e=9+t: v[t] = W[t]-row-d . a_bot[t] ----
    {
        int d = tid & 127;
        int e0 = tid >> 7;                 // 0 or 1
        #pragma unroll
        for (int q = 0; q < 6; ++q) {
            int e = e0 + 2 * q;
            int wi, aoff;
            if (e < 9) { wi = e / 3; aoff = (e % 3) * 2 * HID; }       // a_top[j]
            else       { wi = e - 9; aoff = wi * 2 * HID + HID; }      // a_bot[t]
            const float4* wrow = (const float4*)(Wg + wi * DIM * HID + d * HID);
            const float* arow = &aL[aoff];
            float acc = 0.f;
            #pragma unroll 8
            for (int qq = 0; qq < 32; ++qq) {
                float4 w4 = wrow[qq];
                acc += w4.x * arow[qq * 4 + 0] + w4.y * arow[qq * 4 + 1]
                     + w4.z * arow[qq * 4 + 2] + w4.w * arow[qq * 4 + 3];
            }
            uvL[e * HSTR + d] = acc;
        }
    }
    __syncthreads();

    for (int g = 0; g < G; ++g) {
        const int b = b0 + g;

        // ---- stage h[b] (16 KB fp32) ----
        {
            const float4* src = (const float4*)(hg + (size_t)b * (NNODES * DIM));
            #pragma unroll
            for (int k = 0; k < 4; ++k) {
                int idx = tid + k * 256;          // float4 index 0..1023
                float4 v = src[idx];
                int f = idx << 2;
                int n = f >> 7, d = f & 127;
                *(float4*)&hL[n * HSTR + d] = v;
            }
        }
        __syncthreads();

        // ---- phase 1: logits (105 dots of length 128) ----
        if (tid < 96) {
            int t = tid >> 5, n = tid & 31;
            const float4* hp = (const float4*)&hL[n * HSTR];
            const float4* vp = (const float4*)&uvL[(9 + t) * HSTR];
            float acc = 0.f;
            #pragma unroll 8
            for (int q = 0; q < 32; ++q) {
                float4 x = hp[q], y = vp[q];
                acc += x.x * y.x + x.y * y.y + x.z * y.z + x.w * y.w;
            }
            sNb[t * NNODES + n] = acc;
        } else if (tid < 105) {
            int e = tid - 96;
            const float4* hp = (const float4*)&hL[0];
            const float4* vp = (const float4*)&uvL[e * HSTR];
            float acc = 0.f;
            #pragma unroll 8
            for (int q = 0; q < 32; ++q) {
                float4 x = hp[q], y = vp[q];
                acc += x.x * y.x + x.y * y.y + x.z * y.z + x.w * y.w;
            }
            sTop[e] = acc;
        }
        __syncthreads();

        // ---- phase 2: joint masked softmax -> per-node weights ----
        int wv = tid >> 6;
        if (wv == 0) {
            // ally: (j,n), 3*15=45 lanes; i collapsed (3 exps/lane)
            int lane = tid;
            bool act = lane < 45;
            int j = act ? lane / 15 : 0;
            int n = act ? lane % 15 : 0;
            int mk = 1; float sv = 0.f;
            if (act) {
                mk = (maskg[(size_t)j * NB * NNODES + (size_t)b * NNODES + 1 + n] != 0);
                sv = sNb[j * NNODES + 1 + n];
            }
            float e0 = sTop[0 + j] + sv;
            float e1 = sTop[3 + j] + sv;
            float e2 = sTop[6 + j] + sv;
            bool live = act && (mk == 0);
            float lm = live ? fmaxf(e0, fmaxf(e1, e2)) : -__builtin_inff();
            #pragma unroll
            for (int off = 32; off; off >>= 1) lm = fmaxf(lm, __shfl_xor(lm, off, 64));
            float es = live ? (expf(e0 - lm) + expf(e1 - lm) + expf(e2 - lm)) : 0.f;
            float Z = es;
            #pragma unroll
            for (int off = 32; off; off >>= 1) Z += __shfl_xor(Z, off, 64);
            float w = (live && Z > 0.f) ? es / Z : 0.f;
            if (act) vv[j * NNODES + 1 + n] = w;
        } else if (wv == 1) {
            // opp: (j,n), 3*16=48 lanes
            int lane = tid - 64;
            bool act = lane < 48;
            int j = act ? (lane >> 4) : 0;
            int n = act ? (lane & 15) : 0;
            int mk = 1; float sv = 0.f;
            if (act) {
                mk = (maskg[(size_t)j * NB * NNODES + (size_t)b * NNODES + 16 + n] != 0);
                sv = sNb[j * NNODES + 16 + n];
            }
            float e0 = sTop[0 + j] + sv;
            float e1 = sTop[3 + j] + sv;
            float e2 = sTop[6 + j] + sv;
            bool live = act && (mk == 0);
            float lm = live ? fmaxf(e0, fmaxf(e1, e2)) : -__builtin_inff();
            #pragma unroll
            for (int off = 32; off; off >>= 1) lm = fmaxf(lm, __shfl_xor(lm, off, 64));
            float es = live ? (expf(e0 - lm) + expf(e1 - lm) + expf(e2 - lm)) : 0.f;
            float Z = es;
            #pragma unroll
            for (int off = 32; off; off >>= 1) Z += __shfl_xor(Z, off, 64);
            float w = (live && Z > 0.f) ? es / Z : 0.f;
            if (act) vv[j * NNODES + 16 + n] = w;
        } else if (wv == 2) {
            int lane = tid - 128;
            if (lane < 3) {
                int mk = (maskg[(size_t)lane * NB * NNODES + (size_t)b * NNODES + 0] != 0);
                vv[lane * NNODES + 0] = mk ? 1.f : 0.f;   // self: mask True -> included
            }
        }
        __syncthreads();

        // ---- phase g: gAll[g][t][d] = sum_n vv[t][n] * h[b,n,d] ----
        if (tid < 128) {
            int d = tid;
            float a0 = 0.f, a1 = 0.f, a2 = 0.f;
            #pragma unroll
            for (int n = 0; n < NNODES; ++n) {
                float hv = hL[n * HSTR + d];
                a0 += vv[n] * hv;
                a1 += vv[NNODES + n] * hv;
                a2 += vv[2 * NNODES + n] * hv;
            }
            float* gp = &gAll[g * TT * DIM];
            gp[d] = a0; gp[DIM + d] = a1; gp[2 * DIM + d] = a2;
        }
        __syncthreads();   // also protects hL restage next iteration
    }

    // ---- epilogue: out[b0+g][h] = elu( sum_t sum_d gAll[g][t][d] * W[t][d][h] ) ----
    {
        int h0 = (tid & 31) << 2;   // 4 h per thread
        int dq = tid >> 5;          // 8 d-chunks of 16
        float4 acc[G];
        #pragma unroll
        for (int g = 0; g < G; ++g) acc[g] = make_float4(0.f, 0.f, 0.f, 0.f);
        #pragma unroll
        for (int t = 0; t < TT; ++t) {
            const float* wbase = Wg + t * DIM * HID;
            #pragma unroll 4
            for (int dd = 0; dd < 16; ++dd) {
                int d = dq * 16 + dd;
                float4 wq = *(const float4*)(wbase + d * HID + h0);
                #pragma unroll
                for (int g = 0; g < G; ++g) {
                    float gv = gAll[g * TT * DIM + t * DIM + d];
                    acc[g].x += gv * wq.x;
                    acc[g].y += gv * wq.y;
                    acc[g].z += gv * wq.z;
                    acc[g].w += gv * wq.w;
                }
            }
        }
        #pragma unroll
        for (int g = 0; g < G; ++g)
            *(float4*)&pL[(dq * G + g) * DIM + h0] = acc[g];
    }
    __syncthreads();

    // ---- final: reduce 8 partials, ELU, fp32 store (512 outputs, 2 per thread) ----
    #pragma unroll
    for (int r = 0; r < 2; ++r) {
        int idx = tid + r * 256;        // 0..511
        int g = idx >> 7, h = idx & 127;
        float s = 0.f;
        #pragma unroll
        for (int q = 0; q < 8; ++q) s += pL[q * G * DIM + idx];
        float rr = (s > 0.f) ? s : expm1f(s);
        outg[(size_t)(b0 + g) * DIM + h] = rr;
    }
}

extern "C" void kernel_launch(void* const* d_in, const int* in_sizes, int n_in,
                              void* d_out, int out_size, void* d_ws, size_t ws_size,
                              hipStream_t stream) {
    const float* hg    = (const float*)d_in[0];    // h (B,32,128) fp32
    const int*   maskg = (const int*)d_in[1];      // ALL_TYPE_MASK (3,B,32) 4-byte words
    // d_in[2]=num_ally, d_in[3]=num_opp, d_in[4]=self_type (fixed)
    const float* Wg    = (const float*)d_in[5];    // W (3,128,128) fp32
    const float* ag    = (const float*)d_in[6];    // a (3,256,1) fp32
    float* outg = (float*)d_out;                   // fp32 output (reference output dtype)
    (void)d_ws; (void)ws_size;

    gat_main<<<NBLK, 256, 0, stream>>>(hg, maskg, Wg, ag, outg);
}

// Round 7
// 231.554 us; speedup vs baseline: 1.5776x; 1.5776x over previous
//
#include <hip/hip_runtime.h>
#include <math.h>

#define NB 8192
#define G 4                 // batch rows per block
#define NBLK (NB / G)
#define NNODES 32
#define TT 3
#define DIM 128
#define HID 128
#define HSTR 132            // padded LDS row stride (floats), rows stay 16B-aligned

// Kernel 1: uv[e][d], e<9: u[i=e/3][j=e%3][d] = W[i] row d . a_top[j]
//           e=9+t:    v[t][d]                 = W[t] row d . a_bot[t]
// Identical for all batch rows -> compute ONCE into d_ws (ws validated rounds 2/3).
__global__ __launch_bounds__(128) void gat_prep(
    const float* __restrict__ Wg,   // (3,128,128) fp32
    const float* __restrict__ ag,   // (3,256,1)   fp32
    float* __restrict__ uv)         // (12,128)    fp32
{
    int e = blockIdx.x, d = threadIdx.x;
    int wi, aoff;
    if (e < 9) { wi = e / 3; aoff = (e % 3) * 2 * HID; }        // a_top[j]
    else       { wi = e - 9; aoff = wi * 2 * HID + HID; }       // a_bot[t]
    const float* wrow = Wg + wi * DIM * HID + d * HID;
    const float* arow = ag + aoff;
    float acc = 0.f;
    #pragma unroll 16
    for (int h = 0; h < HID; ++h) acc += wrow[h] * arow[h];
    uv[e * DIM + d] = acc;
}

__global__ __launch_bounds__(256, 4) void gat_main(
    const float* __restrict__ hg,     // (B,32,128) fp32
    const int* __restrict__ maskg,    // (3,B,32) 4-byte bool words
    const float* __restrict__ Wg,     // (3,128,128) fp32
    const float* __restrict__ uv,     // (12,128) fp32 (from d_ws)
    float* __restrict__ outg)         // (B,128) fp32
{
    __shared__ float hL[NNODES * HSTR];   // 16.9 KB current row's h[b]
    __shared__ float uvL[12 * HSTR];      // 6.3 KB
    __shared__ float sTop[16];            // [i*3+j]
    __shared__ float sNb[96];             // [t*32+node]
    __shared__ float vv[TT * NNODES];     // per-node combine weights
    __shared__ float gAll[G * TT * DIM];  // 6.1 KB weighted features
    __shared__ float pL[4 * G * DIM];     // 8 KB epilogue partials (4 d-groups)
    __shared__ int   mvL[G * 96];         // 1.5 KB prefetched masks
    // total ~39.9 KB -> 4 blocks/CU

    const int tid = threadIdx.x;
    const int b0 = blockIdx.x * G;

    // ---- stage uv (1536 elems) ----
    #pragma unroll
    for (int k = 0; k < 6; ++k) {
        int idx = tid + k * 256;
        uvL[(idx >> 7) * HSTR + (idx & 127)] = uv[idx];
    }
    // ---- prefetch all G rows' masks ----
    if (tid < 96) {
        int t = tid >> 5, node = tid & 31;
        #pragma unroll
        for (int g = 0; g < G; ++g)
            mvL[g * 96 + tid] = maskg[(size_t)t * NB * NNODES + (size_t)(b0 + g) * NNODES + node];
    }
    __syncthreads();

    for (int g = 0; g < G; ++g) {
        // ---- stage h[b0+g] (16 KB fp32) ----
        {
            const float4* src = (const float4*)(hg + (size_t)(b0 + g) * (NNODES * DIM));
            #pragma unroll
            for (int k = 0; k < 4; ++k) {
                int idx = tid + k * 256;
                float4 v = src[idx];
                int f = idx << 2;
                *(float4*)&hL[(f >> 7) * HSTR + (f & 127)] = v;
            }
        }
        __syncthreads();

        // ---- phase 1: 105 dots split into 210 half-dots + shfl combine ----
        if (tid < 210) {
            int task = tid >> 1, half = tid & 1;
            const float4 *hp, *vp;
            if (task < 96) {
                int t = task >> 5, n = task & 31;
                hp = (const float4*)&hL[n * HSTR];
                vp = (const float4*)&uvL[(9 + t) * HSTR];
            } else {
                int e = task - 96;
                hp = (const float4*)&hL[0];
                vp = (const float4*)&uvL[e * HSTR];
            }
            hp += half * 16; vp += half * 16;
            float acc = 0.f;
            #pragma unroll
            for (int q = 0; q < 16; ++q) {
                float4 x = hp[q], y = vp[q];
                acc += x.x * y.x + x.y * y.y + x.z * y.z + x.w * y.w;
            }
            acc += __shfl_xor(acc, 1, 64);
            if (!half) {
                if (task < 96) sNb[task] = acc;
                else           sTop[task - 96] = acc;
            }
        }
        __syncthreads();

        // ---- phase 2: joint masked softmax -> per-node weights (LDS-only) ----
        int wv = tid >> 6;
        if (wv == 0) {
            // ally: (j,n), 45 lanes; i collapsed (3 exps/lane)
            int lane = tid;
            bool act = lane < 45;
            int j = act ? lane / 15 : 0;
            int n = act ? lane % 15 : 0;
            int mk = 1; float sv = 0.f;
            if (act) {
                mk = mvL[g * 96 + j * 32 + 1 + n];
                sv = sNb[j * 32 + 1 + n];
            }
            float e0 = sTop[0 + j] + sv;
            float e1 = sTop[3 + j] + sv;
            float e2 = sTop[6 + j] + sv;
            bool live = act && (mk == 0);
            float lm = live ? fmaxf(e0, fmaxf(e1, e2)) : -__builtin_inff();
            #pragma unroll
            for (int off = 32; off; off >>= 1) lm = fmaxf(lm, __shfl_xor(lm, off, 64));
            float es = live ? (expf(e0 - lm) + expf(e1 - lm) + expf(e2 - lm)) : 0.f;
            float Z = es;
            #pragma unroll
            for (int off = 32; off; off >>= 1) Z += __shfl_xor(Z, off, 64);
            float w = (live && Z > 0.f) ? es / Z : 0.f;
            if (act) vv[j * NNODES + 1 + n] = w;
        } else if (wv == 1) {
            // opp: (j,n), 48 lanes
            int lane = tid - 64;
            bool act = lane < 48;
            int j = act ? (lane >> 4) : 0;
            int n = act ? (lane & 15) : 0;
            int mk = 1; float sv = 0.f;
            if (act) {
                mk = mvL[g * 96 + j * 32 + 16 + n];
                sv = sNb[j * 32 + 16 + n];
            }
            float e0 = sTop[0 + j] + sv;
            float e1 = sTop[3 + j] + sv;
            float e2 = sTop[6 + j] + sv;
            bool live = act && (mk == 0);
            float lm = live ? fmaxf(e0, fmaxf(e1, e2)) : -__builtin_inff();
            #pragma unroll
            for (int off = 32; off; off >>= 1) lm = fmaxf(lm, __shfl_xor(lm, off, 64));
            float es = live ? (expf(e0 - lm) + expf(e1 - lm) + expf(e2 - lm)) : 0.f;
            float Z = es;
            #pragma unroll
            for (int off = 32; off; off >>= 1) Z += __shfl_xor(Z, off, 64);
            float w = (live && Z > 0.f) ? es / Z : 0.f;
            if (act) vv[j * NNODES + 16 + n] = w;
        } else if (wv == 2) {
            int lane = tid - 128;
            if (lane < 3)
                vv[lane * NNODES + 0] = mvL[g * 96 + lane * 32 + 0] ? 1.f : 0.f; // self: True -> included
        }
        __syncthreads();

        // ---- phase g: gAll[g][t][d] = sum_n vv[t][n] * h[n][d] ----
        if (tid < 128) {
            int d = tid;
            float a0 = 0.f, a1 = 0.f, a2 = 0.f;
            #pragma unroll
            for (int n = 0; n < NNODES; ++n) {
                float hv = hL[n * HSTR + d];
                a0 += vv[n] * hv;
                a1 += vv[NNODES + n] * hv;
                a2 += vv[2 * NNODES + n] * hv;
            }
            float* gp = &gAll[g * TT * DIM];
            gp[d] = a0; gp[DIM + d] = a1; gp[2 * DIM + d] = a2;
        }
        __syncthreads();   // also protects hL restage next iteration
    }

    // ---- epilogue: out[b0+g][h] = sum_t sum_d gAll[g][t][d] * W[t][d][h] ----
    // 256 threads = 64 h-pairs x 4 d-groups of 32; W streamed once per block from L2.
    {
        int hp2 = tid & 63;          // h0 = 2*hp2
        int dq  = tid >> 6;          // 0..3
        float2 acc[G];
        #pragma unroll
        for (int g = 0; g < G; ++g) acc[g] = make_float2(0.f, 0.f);
        #pragma unroll
        for (int t = 0; t < TT; ++t) {
            const float* wbase = Wg + ((size_t)t * DIM + dq * 32) * HID;
            const float* gbase = &gAll[t * DIM + dq * 32];
            #pragma unroll 8
            for (int dd = 0; dd < 32; ++dd) {
                float2 wq = *(const float2*)(wbase + dd * HID + 2 * hp2);
                #pragma unroll
                for (int g = 0; g < G; ++g) {
                    float gv = gbase[g * TT * DIM + dd];   // wave-uniform -> LDS broadcast
                    acc[g].x += gv * wq.x;
                    acc[g].y += gv * wq.y;
                }
            }
        }
        #pragma unroll
        for (int g = 0; g < G; ++g)
            *(float2*)&pL[(dq * G + g) * DIM + 2 * hp2] = acc[g];
    }
    __syncthreads();

    // ---- final: reduce 4 partials, ELU, fp32 store ----
    #pragma unroll
    for (int r = 0; r < 2; ++r) {
        int idx = tid + r * 256;        // 0..511 -> (g, h)
        int g = idx >> 7, h = idx & 127;
        float s = pL[idx] + pL[512 + idx] + pL[1024 + idx] + pL[1536 + idx];
        float rr = (s > 0.f) ? s : expm1f(s);
        outg[(size_t)(b0 + g) * DIM + h] = rr;
    }
}

extern "C" void kernel_launch(void* const* d_in, const int* in_sizes, int n_in,
                              void* d_out, int out_size, void* d_ws, size_t ws_size,
                              hipStream_t stream) {
    const float* hg    = (const float*)d_in[0];    // h (B,32,128) fp32
    const int*   maskg = (const int*)d_in[1];      // ALL_TYPE_MASK (3,B,32) 4-byte words
    // d_in[2]=num_ally, d_in[3]=num_opp, d_in[4]=self_type (fixed)
    const float* Wg    = (const float*)d_in[5];    // W (3,128,128) fp32
    const float* ag    = (const float*)d_in[6];    // a (3,256,1) fp32
    float* uv = (float*)d_ws;                      // 12*128 fp32 scratch (validated)
    float* outg = (float*)d_out;                   // fp32 output

    gat_prep<<<12, 128, 0, stream>>>(Wg, ag, uv);
    gat_main<<<NBLK, 256, 0, stream>>>(hg, maskg, Wg, uv, outg);
}